// Round 15
// baseline (1865.532 us; speedup 1.0000x reference)
//
#include <hip/hip_runtime.h>
#include <hip/hip_bf16.h>

typedef unsigned short u16;
typedef unsigned int u32;
using short8 = __attribute__((ext_vector_type(8))) short;
using f32x4  = __attribute__((ext_vector_type(4))) float;

// ---------- helpers ----------
__device__ __forceinline__ u16 f2bu(float f) {            // f32 -> bf16 bits (RNE)
  u32 u = __builtin_bit_cast(u32, f);
  u32 r = u + 0x7fffu + ((u >> 16) & 1u);
  return (u16)(r >> 16);
}
__device__ __forceinline__ float bu2f(u16 u) {             // bf16 bits -> f32
  u32 x = ((u32)u) << 16;
  return __builtin_bit_cast(float, x);
}
__device__ __forceinline__ float waveRedSum(float v) {
  #pragma unroll
  for (int off = 32; off > 0; off >>= 1) v += __shfl_xor(v, off, 64);
  return v;
}
__device__ __forceinline__ void gload16(const void* g, void* l) {
  __builtin_amdgcn_global_load_lds((const __attribute__((address_space(1))) u32*)g,
                                   (__attribute__((address_space(3))) u32*)l, 16, 0, 0);
}

// ---------- 128x128 GEMM, BK=64 + both-sides XOR swizzle (proven r13), T1 XCD swizzle ----------
// MODE 0: Cf f32 | MODE 1: Cb bf16 | MODE 2: moe1 gather-A(tok)+relu -> Cb
// MODE 3: moe2 scatter*prob | MODE 5: Cb += acc+bias (bf16 RMW, residual fusion)
template<int MODE>
__global__ __launch_bounds__(256) void gemm_bt(
    const u16* __restrict__ A, const u16* __restrict__ Bt, const float* __restrict__ bias,
    float* __restrict__ Cf, u16* __restrict__ Cb, u16* __restrict__ M0, u16* __restrict__ M1,
    const int* __restrict__ tok, const float* __restrict__ prob, const int* __restrict__ slot,
    const int* __restrict__ poff, const int* __restrict__ cnts,
    int N, int K)
{
  const int gx = gridDim.x;
  const int nwg = gx * gridDim.y;
  int lid = blockIdx.y * gx + blockIdx.x;
  lid = (lid & 7) * (nwg >> 3) + (lid >> 3);
  const int brow = (lid / gx) << 7, bcol = (lid % gx) << 7;

  int e = 0, rowEnd = 0;
  const u16* Bw = Bt;
  const float* bw = bias;
  if constexpr (MODE == 2 || MODE == 3) {
    if (brow >= poff[4]) return;
    #pragma unroll
    for (int q = 1; q < 4; ++q) if (brow >= poff[q]) e = q;
    rowEnd = poff[e] + cnts[e];
    Bw = Bt + (size_t)e * N * K;
    bw = bias + e * N;
  }

  __shared__ __align__(16) u16 As[128 * 64];
  __shared__ __align__(16) u16 Bs[128 * 64];
  const int tid = threadIdx.x;
  const int wave = tid >> 6, lane = tid & 63;
  const int wr = wave >> 1, wc = wave & 1;
  const int r = lane & 15, kg = lane >> 4;

  f32x4 acc[4][4];
  #pragma unroll
  for (int m = 0; m < 4; ++m)
    #pragma unroll
    for (int n = 0; n < 4; ++n) acc[m][n] = f32x4{0.f, 0.f, 0.f, 0.f};

  const u16* aSrc[4];
  const u16* bSrc[4];
  const u16* Bb = Bw + (size_t)bcol * K;
  #pragma unroll
  for (int q = 0; q < 4; ++q) {
    const int cid = (q << 8) + (wave << 6) + lane;
    const int row = cid >> 3, c = cid & 7;
    const int scol = (c ^ (row & 7)) << 3;
    size_t ar;
    if constexpr (MODE == 2) {
      const int g = brow + row;
      ar = (size_t)tok[(g < rowEnd) ? g : poff[e]];
    } else {
      ar = (size_t)(brow + row);
    }
    aSrc[q] = A + ar * K + scol;
    bSrc[q] = Bb + (size_t)row * K + scol;
  }
  const int swz0 = (kg ^ (r & 7)) << 3;
  const int swz1 = ((4 + kg) ^ (r & 7)) << 3;

  for (int k0 = 0; k0 < K; k0 += 64) {
    __syncthreads();
    #pragma unroll
    for (int q = 0; q < 4; ++q) {
      gload16(aSrc[q] + k0, &As[(((q << 8) + (wave << 6))) << 3]);
      gload16(bSrc[q] + k0, &Bs[(((q << 8) + (wave << 6))) << 3]);
    }
    __syncthreads();
    #pragma unroll
    for (int ks = 0; ks < 2; ++ks) {
      const int swz = ks ? swz1 : swz0;
      short8 a[4], b[4];
      #pragma unroll
      for (int m = 0; m < 4; ++m)
        a[m] = *(const short8*)&As[(((wr << 6) + (m << 4) + r) << 6) + swz];
      #pragma unroll
      for (int n = 0; n < 4; ++n)
        b[n] = *(const short8*)&Bs[(((wc << 6) + (n << 4) + r) << 6) + swz];
      #pragma unroll
      for (int m = 0; m < 4; ++m)
        #pragma unroll
        for (int n = 0; n < 4; ++n)
          acc[m][n] = __builtin_amdgcn_mfma_f32_16x16x32_bf16(a[m], b[n], acc[m][n], 0, 0, 0);
    }
  }

  if constexpr (MODE == 3) {
    #pragma unroll
    for (int m = 0; m < 4; ++m) {
      #pragma unroll
      for (int i4 = 0; i4 < 4; ++i4) {
        const int row = brow + (wr << 6) + (m << 4) + (kg << 2) + i4;
        if (row < rowEnd) {
          const int t = tok[row];
          const float pp = prob[row];
          u16* dst = slot[row] ? M1 : M0;
          #pragma unroll
          for (int n = 0; n < 4; ++n) {
            const int col = bcol + (wc << 6) + (n << 4) + r;
            dst[(size_t)t * N + col] = f2bu((acc[m][n][i4] + bw[col]) * pp);
          }
        }
      }
    }
  } else {
    #pragma unroll
    for (int m = 0; m < 4; ++m) {
      #pragma unroll
      for (int n = 0; n < 4; ++n) {
        const int col = bcol + (wc << 6) + (n << 4) + r;
        const float bv = bw[col];
        #pragma unroll
        for (int i4 = 0; i4 < 4; ++i4) {
          const int row = brow + (wr << 6) + (m << 4) + (kg << 2) + i4;
          const float v = acc[m][n][i4] + bv;
          const size_t off = (size_t)row * N + col;
          if constexpr (MODE == 0) Cf[off] = v;
          else if constexpr (MODE == 1) Cb[off] = f2bu(v);
          else if constexpr (MODE == 5) Cb[off] = f2bu(bu2f(Cb[off]) + v);  // residual fusion
          else Cb[off] = f2bu(fmaxf(v, 0.f));
        }
      }
    }
  }
}

// ---------- transpose+convert tile body v2: 64(k) x 32(n), vectorized short8 writes ----------
__device__ __forceinline__ void tconv_tile64(const float* __restrict__ s, u16* __restrict__ d,
                                             int K, int N, int n0, int k0)
{
  __shared__ float t[64][33];
  const int x = threadIdx.x, y = threadIdx.y;     // (32,8)
  #pragma unroll
  for (int j = 0; j < 8; ++j)
    t[y + 8 * j][x] = s[(size_t)(k0 + y + 8 * j) * N + n0 + x];
  __syncthreads();
  const int tid = y * 32 + x;
  const int nl = tid >> 3, kl = (tid & 7) << 3;
  short8 w;
  #pragma unroll
  for (int jj = 0; jj < 8; ++jj) w[jj] = (short)f2bu(t[kl + jj][nl]);
  *(short8*)(d + (size_t)(n0 + nl) * K + k0 + kl) = w;
}

// ---------- generic transpose+convert (proj only): grid (N/32, K/64) ----------
__global__ __launch_bounds__(256) void tconv_kernel(const float* __restrict__ src, u16* __restrict__ dst,
                                                    int K, int N)
{
  tconv_tile64(src, dst, K, N, blockIdx.x << 5, blockIdx.y << 6);
}

// ---------- per-layer fused weight conversion (10240 blocks) ----------
__global__ __launch_bounds__(256) void tconv4_kernel(
    const float* __restrict__ wqkv_s, const float* __restrict__ wout_s,
    const float* __restrict__ we1_s, const float* __restrict__ we2_s,
    u16* __restrict__ wqkv_d, u16* __restrict__ wout_d,
    u16* __restrict__ we1_d, u16* __restrict__ we2_d)
{
  const int bid = blockIdx.x;
  if (bid < 1536) {            // Wqkv: K=1024 (16 k-tiles), N=3072 (96 n-tiles)
    tconv_tile64(wqkv_s, wqkv_d, 1024, 3072, (bid % 96) << 5, (bid / 96) << 6);
  } else if (bid < 2048) {     // Wout: 16 x 32
    const int b2 = bid - 1536;
    tconv_tile64(wout_s, wout_d, 1024, 1024, (b2 % 32) << 5, (b2 / 32) << 6);
  } else if (bid < 6144) {     // We1[e]: K=1024 (16), N=2048 (64)
    const int b2 = bid - 2048;
    const int ee = b2 >> 10, rr = b2 & 1023;
    tconv_tile64(we1_s + (size_t)ee * 2048 * 1024, we1_d + (size_t)ee * 2048 * 1024,
                 1024, 2048, (rr % 64) << 5, (rr / 64) << 6);
  } else {                     // We2[e]: K=2048 (32), N=1024 (32)
    const int b2 = bid - 6144;
    const int ee = b2 >> 10, rr = b2 & 1023;
    tconv_tile64(we2_s + (size_t)ee * 1024 * 2048, we2_d + (size_t)ee * 1024 * 2048,
                 2048, 1024, (rr % 32) << 5, (rr / 32) << 6);
  }
}

// ---------- f32 -> bf16 elementwise ----------
__global__ __launch_bounds__(256) void conv_kernel(const float* __restrict__ in, u16* __restrict__ out)
{
  const size_t i = ((size_t)blockIdx.x * 256 + threadIdx.x) * 4;
  float4 v = *(const float4*)(in + i);
  *(ushort4*)(out + i) = make_ushort4(f2bu(v.x), f2bu(v.y), f2bu(v.z), f2bu(v.w));
}

// ---------- add sinusoidal positional encoding, bf16 in-place ----------
__global__ __launch_bounds__(256) void pe_kernel(u16* __restrict__ Xb)
{
  const int idx = (blockIdx.x * 256 + threadIdx.x) * 4;
  const int s = (idx >> 10) & 127;
  ushort4 v = *(const ushort4*)(Xb + idx);
  float o[4];
  const u16 vv[4] = {v.x, v.y, v.z, v.w};
  #pragma unroll
  for (int j = 0; j < 4; ++j) {
    const int d = (idx + j) & 1023;
    const float de = (float)(d & ~1);
    const float ang = (float)s * expf(de * (-9.210340371976184f / 1024.f));
    const float pe = (d & 1) ? cosf(ang) : sinf(ang);
    o[j] = bu2f(vv[j]) + pe;
  }
  *(ushort4*)(Xb + idx) = make_ushort4(f2bu(o[0]), f2bu(o[1]), f2bu(o[2]), f2bu(o[3]));
}

// ---------- pure LN (residual pre-added by gemm_bt<5>) + router, bf16 in-place ----------
__global__ __launch_bounds__(256) void ln_kernel(u16* __restrict__ Xb,
    const float* __restrict__ g, const float* __restrict__ be,
    const float* __restrict__ rw, const float* __restrict__ rb,
    int* __restrict__ choice, float* __restrict__ prob2)
{
  const int token = blockIdx.x;
  const size_t base = (size_t)token << 10;
  const int tid = threadIdx.x;
  const int d0 = tid << 2;
  ushort4 xv = *(const ushort4*)(Xb + base + d0);
  float vals[4] = {bu2f(xv.x), bu2f(xv.y), bu2f(xv.z), bu2f(xv.w)};
  float s = 0.f, s2 = 0.f;
  #pragma unroll
  for (int j = 0; j < 4; ++j) { s += vals[j]; s2 += vals[j] * vals[j]; }
  s = waveRedSum(s); s2 = waveRedSum(s2);
  __shared__ float rs[4], rs2[4];
  __shared__ float rl[4][4];
  const int wave = tid >> 6, lane = tid & 63;
  if (lane == 0) { rs[wave] = s; rs2[wave] = s2; }
  __syncthreads();
  s = rs[0] + rs[1] + rs[2] + rs[3];
  s2 = rs2[0] + rs2[1] + rs2[2] + rs2[3];
  const float mean = s * (1.f / 1024.f);
  const float var = s2 * (1.f / 1024.f) - mean * mean;
  const float inv = rsqrtf(var + 1e-5f);
  const float4 gv = *(const float4*)(g + d0);
  const float4 bv = *(const float4*)(be + d0);
  float y[4];
  y[0] = (vals[0] - mean) * inv * gv.x + bv.x;
  y[1] = (vals[1] - mean) * inv * gv.y + bv.y;
  y[2] = (vals[2] - mean) * inv * gv.z + bv.z;
  y[3] = (vals[3] - mean) * inv * gv.w + bv.w;
  *(ushort4*)(Xb + base + d0) = make_ushort4(f2bu(y[0]), f2bu(y[1]), f2bu(y[2]), f2bu(y[3]));
  float l0 = 0.f, l1 = 0.f, l2 = 0.f, l3 = 0.f;
  #pragma unroll
  for (int j = 0; j < 4; ++j) {
    const float4 w = *(const float4*)(rw + ((size_t)(d0 + j) << 2));
    l0 += y[j] * w.x; l1 += y[j] * w.y; l2 += y[j] * w.z; l3 += y[j] * w.w;
  }
  l0 = waveRedSum(l0); l1 = waveRedSum(l1); l2 = waveRedSum(l2); l3 = waveRedSum(l3);
  if (lane == 0) { rl[wave][0] = l0; rl[wave][1] = l1; rl[wave][2] = l2; rl[wave][3] = l3; }
  __syncthreads();
  if (tid == 0) {
    float v[4];
    #pragma unroll
    for (int q = 0; q < 4; ++q)
      v[q] = rl[0][q] + rl[1][q] + rl[2][q] + rl[3][q] + rb[q];
    int i1 = 0;
    for (int q = 1; q < 4; ++q) if (v[q] > v[i1]) i1 = q;   // earliest-max tie rule
    int i2 = (i1 == 0) ? 1 : 0;
    for (int q = 0; q < 4; ++q) if (q != i1 && v[q] > v[i2]) i2 = q;
    const float p2 = __expf(v[i2] - v[i1]);
    const float is = 1.f / (1.f + p2);
    choice[token] = i1 | (i2 << 8);
    prob2[token * 2]     = is;
    prob2[token * 2 + 1] = p2 * is;
  }
}

// ---------- fused residual + LN (2 MOE slots) + optional pooling score: bf16 in-place ----------
__global__ __launch_bounds__(256) void ln2_kernel(u16* __restrict__ Xb,
    const u16* __restrict__ R0, const u16* __restrict__ R1,
    const float* __restrict__ g, const float* __restrict__ be,
    const float* __restrict__ aw, const float* __restrict__ ab, float* __restrict__ S)
{
  const int token = blockIdx.x;
  const size_t base = (size_t)token << 10;
  const int tid = threadIdx.x;
  const int d0 = tid << 2;
  ushort4 xv = *(const ushort4*)(Xb + base + d0);
  ushort4 r0 = *(const ushort4*)(R0 + base + d0);
  ushort4 r1 = *(const ushort4*)(R1 + base + d0);
  float vals[4] = {bu2f(xv.x) + (bu2f(r0.x) + bu2f(r1.x)),
                   bu2f(xv.y) + (bu2f(r0.y) + bu2f(r1.y)),
                   bu2f(xv.z) + (bu2f(r0.z) + bu2f(r1.z)),
                   bu2f(xv.w) + (bu2f(r0.w) + bu2f(r1.w))};
  float s = 0.f, s2 = 0.f;
  #pragma unroll
  for (int j = 0; j < 4; ++j) { s += vals[j]; s2 += vals[j] * vals[j]; }
  s = waveRedSum(s); s2 = waveRedSum(s2);
  __shared__ float rs[4], rs2[4];
  __shared__ float rsc[4];
  const int wave = tid >> 6, lane = tid & 63;
  if (lane == 0) { rs[wave] = s; rs2[wave] = s2; }
  __syncthreads();
  s = rs[0] + rs[1] + rs[2] + rs[3];
  s2 = rs2[0] + rs2[1] + rs2[2] + rs2[3];
  const float mean = s * (1.f / 1024.f);
  const float var = s2 * (1.f / 1024.f) - mean * mean;
  const float inv = rsqrtf(var + 1e-5f);
  const float4 gv = *(const float4*)(g + d0);
  const float4 bv = *(const float4*)(be + d0);
  float y[4];
  y[0] = (vals[0] - mean) * inv * gv.x + bv.x;
  y[1] = (vals[1] - mean) * inv * gv.y + bv.y;
  y[2] = (vals[2] - mean) * inv * gv.z + bv.z;
  y[3] = (vals[3] - mean) * inv * gv.w + bv.w;
  *(ushort4*)(Xb + base + d0) = make_ushort4(f2bu(y[0]), f2bu(y[1]), f2bu(y[2]), f2bu(y[3]));
  if (aw) {
    const float4 av = *(const float4*)(aw + d0);
    float sc = y[0] * av.x + y[1] * av.y + y[2] * av.z + y[3] * av.w;
    sc = waveRedSum(sc);
    if (lane == 0) rsc[wave] = sc;
    __syncthreads();
    if (tid == 0) S[token] = rsc[0] + rsc[1] + rsc[2] + rsc[3] + ab[0];
  }
}

// ---------- MFMA attention per (b,h): Pb aliased onto Kb -> 69.6 KB LDS, 2 blocks/CU ----------
#define LDW 136
__global__ __launch_bounds__(256) void attn_mfma_kernel(const u16* __restrict__ QKVb, u16* __restrict__ ATTb)
{
  __shared__ __align__(16) u16 Kb[128 * LDW];
  __shared__ __align__(16) u16 Vt[128 * LDW];
  u16* Pb = Kb;
  const int b = blockIdx.x >> 3, h = blockIdx.x & 7;
  const int tid = threadIdx.x;
  const int wave = tid >> 6, lane = tid & 63;
  const int r = lane & 15, kg = lane >> 4;
  const u16* base = QKVb + (size_t)b * 128 * 3072 + h * 128;

  for (int i = tid; i < 128 * 16; i += 256) {
    const int row = i >> 4, c8 = (i & 15) << 3;
    *(short8*)&Kb[row * LDW + c8] = *(const short8*)(base + (size_t)row * 3072 + 1024 + c8);
  }
  for (int i = tid; i < 128 * 128; i += 256) {
    const int d = i & 127, key = i >> 7;
    Vt[d * LDW + key] = base[(size_t)key * 3072 + 2048 + d];
  }

  short8 a[2][4];
  #pragma unroll
  for (int m = 0; m < 2; ++m) {
    const int row = wave * 32 + m * 16 + r;
    const u16* qp = base + (size_t)row * 3072;
    #pragma unroll
    for (int ks = 0; ks < 4; ++ks)
      a[m][ks] = *(const short8*)(qp + ks * 32 + kg * 8);
  }
  __syncthreads();

  f32x4 acc[2][8];
  #pragma unroll
  for (int m = 0; m < 2; ++m)
    #pragma unroll
    for (int n = 0; n < 8; ++n) acc[m][n] = f32x4{0.f, 0.f, 0.f, 0.f};
  #pragma unroll
  for (int n = 0; n < 8; ++n) {
    #pragma unroll
    for (int ks = 0; ks < 4; ++ks) {
      short8 bf = *(const short8*)&Kb[(n * 16 + r) * LDW + ks * 32 + kg * 8];
      #pragma unroll
      for (int m = 0; m < 2; ++m)
        acc[m][n] = __builtin_amdgcn_mfma_f32_16x16x32_bf16(a[m][ks], bf, acc[m][n], 0, 0, 0);
    }
  }
  __syncthreads();   // all waves done reading Kb before Pb (same memory) is written

  const float sc = 0.08838834764831845f;
  #pragma unroll
  for (int m = 0; m < 2; ++m) {
    #pragma unroll
    for (int i = 0; i < 4; ++i) {
      float mx = -1e30f;
      #pragma unroll
      for (int n = 0; n < 8; ++n) mx = fmaxf(mx, acc[m][n][i]);
      #pragma unroll
      for (int msk = 1; msk < 16; msk <<= 1) mx = fmaxf(mx, __shfl_xor(mx, msk, 64));
      float s = 0.f;
      #pragma unroll
      for (int n = 0; n < 8; ++n) { float pv = __expf((acc[m][n][i] - mx) * sc); acc[m][n][i] = pv; s += pv; }
      #pragma unroll
      for (int msk = 1; msk < 16; msk <<= 1) s += __shfl_xor(s, msk, 64);
      const float inv = 1.f / s;
      #pragma unroll
      for (int n = 0; n < 8; ++n) {
        const int prow = wave * 32 + m * 16 + kg * 4 + i;
        Pb[prow * LDW + n * 16 + r] = f2bu(acc[m][n][i] * inv);
      }
    }
  }

  f32x4 oacc[2][8];
  #pragma unroll
  for (int m = 0; m < 2; ++m)
    #pragma unroll
    for (int n = 0; n < 8; ++n) oacc[m][n] = f32x4{0.f, 0.f, 0.f, 0.f};
  #pragma unroll
  for (int ks = 0; ks < 4; ++ks) {
    short8 pa[2];
    #pragma unroll
    for (int m = 0; m < 2; ++m)
      pa[m] = *(const short8*)&Pb[(wave * 32 + m * 16 + r) * LDW + ks * 32 + kg * 8];
    #pragma unroll
    for (int n = 0; n < 8; ++n) {
      short8 vb = *(const short8*)&Vt[(n * 16 + r) * LDW + ks * 32 + kg * 8];
      #pragma unroll
      for (int m = 0; m < 2; ++m)
        oacc[m][n] = __builtin_amdgcn_mfma_f32_16x16x32_bf16(pa[m], vb, oacc[m][n], 0, 0, 0);
    }
  }

  u16* op = ATTb + ((size_t)b * 128) * 1024 + h * 128;
  #pragma unroll
  for (int m = 0; m < 2; ++m) {
    #pragma unroll
    for (int n = 0; n < 8; ++n) {
      #pragma unroll
      for (int i = 0; i < 4; ++i) {
        const int row = wave * 32 + m * 16 + kg * 4 + i;
        op[(size_t)row * 1024 + n * 16 + r] = f2bu(oacc[m][n][i]);
      }
    }
  }
}
#undef LDW

// ---------- build lists: 4 waves, wave e scans for expert e (atomic-free, deterministic) ----------
__global__ __launch_bounds__(256) void build_lists_kernel(
    const int* __restrict__ choice, const float* __restrict__ prob2,
    int* __restrict__ cnt, int* __restrict__ poff,
    int* __restrict__ tok, float* __restrict__ prob, int* __restrict__ slot)
{
  const int tid = threadIdx.x;
  const int e = tid >> 6, lane = tid & 63;
  const int t0 = lane << 7;
  int mycount = 0;
  for (int j = 0; j < 128; ++j) {
    const int c = choice[t0 + j];
    mycount += (((c & 255) == e) || ((c >> 8) == e)) ? 1 : 0;
  }
  int incl = mycount;
  #pragma unroll
  for (int off = 1; off < 64; off <<= 1) {
    const int t = __shfl_up(incl, off, 64);
    if (lane >= off) incl += t;
  }
  __shared__ int totals[4];
  if (lane == 63) totals[e] = incl;
  __syncthreads();
  int base = 0;
  #pragma unroll
  for (int q = 0; q < 4; ++q)
    if (q < e) base += (totals[q] + 255) & ~255;
  int pos = base + incl - mycount;
  for (int j = 0; j < 128; ++j) {
    const int token = t0 + j;
    const int c = choice[token];
    const int m = ((c & 255) == e) ? 1 : (((c >> 8) == e) ? 2 : 0);
    if (m) {
      tok[pos] = token;
      prob[pos] = prob2[token * 2 + (m - 1)];
      slot[pos] = m - 1;
      ++pos;
    }
  }
  if (lane == 0) {
    cnt[e] = totals[e];
    poff[e] = base;
    if (e == 3) poff[4] = base + ((totals[3] + 255) & ~255);
  }
}

// ---------- softmax over S per batch + weighted pool (bf16 X) ----------
__global__ __launch_bounds__(256) void pool_kernel(const u16* __restrict__ Xb, const float* __restrict__ S,
                                                   float* __restrict__ P)
{
  const int b = blockIdx.x;
  const int tid = threadIdx.x;
  __shared__ float p[128];
  if (tid < 128) p[tid] = S[b * 128 + tid];
  __syncthreads();
  float mx = -1e30f;
  for (int t = 0; t < 128; ++t) mx = fmaxf(mx, p[t]);
  float sum = 0.f;
  for (int t = 0; t < 128; ++t) sum += __expf(p[t] - mx);
  const float inv = 1.f / sum;
  __syncthreads();
  if (tid < 128) p[tid] = __expf(p[tid] - mx) * inv;
  __syncthreads();
  float acc[4] = {0.f, 0.f, 0.f, 0.f};
  for (int t = 0; t < 128; ++t) {
    const float pt = p[t];
    const u16* xp = Xb + ((size_t)(b * 128 + t) << 10) + tid;
    #pragma unroll
    for (int j = 0; j < 4; ++j) acc[j] += pt * bu2f(xp[j << 8]);
  }
  #pragma unroll
  for (int j = 0; j < 4; ++j) P[((size_t)b << 10) + tid + (j << 8)] = acc[j];
}

// ---------- task heads ----------
__global__ __launch_bounds__(256) void heads_kernel(const float* __restrict__ P, const float* __restrict__ hw,
    const float* __restrict__ hb, float* __restrict__ out)
{
  const int idx = blockIdx.x * 4 + (threadIdx.x >> 6);
  const int lane = threadIdx.x & 63;
  const int t = idx >> 8, b = (idx >> 2) & 63, c = idx & 3;
  const float* pp = P + ((size_t)b << 10);
  const float* wp = hw + (size_t)t * 4096 + c;
  float s = 0.f;
  #pragma unroll
  for (int j = 0; j < 16; ++j) { const int k = lane + (j << 6); s += pp[k] * wp[(size_t)k << 2]; }
  s = waveRedSum(s);
  if (lane == 0) out[idx] = s + hb[t * 4 + c];
}

// ---------- host ----------
extern "C" void kernel_launch(void* const* d_in, const int* in_sizes, int n_in,
                              void* d_out, int out_size, void* d_ws, size_t ws_size,
                              hipStream_t stream)
{
  (void)in_sizes; (void)n_in; (void)out_size; (void)ws_size;
  const float* vis        = (const float*)d_in[0];
  const float* proj_w     = (const float*)d_in[1];
  const float* proj_b     = (const float*)d_in[2];
  const float* in_proj_w  = (const float*)d_in[3];
  const float* in_proj_b  = (const float*)d_in[4];
  const float* out_proj_w = (const float*)d_in[5];
  const float* out_proj_b = (const float*)d_in[6];
  const float* ln1_g      = (const float*)d_in[7];
  const float* ln1_b      = (const float*)d_in[8];
  const float* ln2_g      = (const float*)d_in[9];
  const float* ln2_b      = (const float*)d_in[10];
  const float* router_w   = (const float*)d_in[11];
  const float* router_b   = (const float*)d_in[12];
  const float* ew1        = (const float*)d_in[13];
  const float* eb1        = (const float*)d_in[14];
  const float* ew2        = (const float*)d_in[15];
  const float* eb2        = (const float*)d_in[16];
  const float* attn_w     = (const float*)d_in[17];
  const float* attn_b     = (const float*)d_in[18];
  const float* heads_w    = (const float*)d_in[19];
  const float* heads_b    = (const float*)d_in[20];
  float* out = (float*)d_out;

  char* p = (char*)d_ws;
  auto take = [&](size_t bytes) -> char* {
    char* q = p; p += (bytes + 255) & ~(size_t)255; return q;
  };
  u16*   Xb   = (u16*)  take(8192ULL * 1024 * 2);
  char*  QKVr = take(104857600ULL);              // QKVb(50.3M) | [H 71.3M][MOE0b][MOE1b]
  u16*   ATTb = (u16*)  take(8192ULL * 1024 * 2);
  int*   CNT  = (int*)  take(4 * 4);
  int*   POFF = (int*)  take(5 * 4);
  int*   CHOICE = (int*)take(8192ULL * 4);
  float* PROB2  = (float*)take(8192ULL * 2 * 4);
  int*   TOK  = (int*)  take(17408ULL * 4);
  float* PROB = (float*)take(17408ULL * 4);
  int*   SLOT = (int*)  take(17408ULL * 4);
  float* S    = (float*)take(8192ULL * 4);
  float* POOL = (float*)take(64ULL * 1024 * 4);
  u16*   Wqkv = (u16*)  take(3072ULL * 1024 * 2);
  u16*   Wout = (u16*)  take(1024ULL * 1024 * 2);
  u16*   We1  = (u16*)  take(4ULL * 2048 * 1024 * 2);
  u16*   We2  = (u16*)  take(4ULL * 1024 * 2048 * 2);
  // aliases into QKVr (time-disjoint): QKVb [qkv->attn]; H [moe1->moe2]; MOEb [moe2->ln2]
  u16*   QKVb  = (u16*)QKVr;
  u16*   H     = (u16*)QKVr;                      // 17408 x 2048 bf16 = 71.3MB
  u16*   MOE0b = (u16*)(QKVr + 71303168);
  u16*   MOE1b = (u16*)(QKVr + 71303168 + 16777216);
  u16*   Wproj = We1;                              // pre-layer-0 only
  u16*   VISb  = (u16*)QKVr;                       // pre-layer-0 only (25.2MB)

  const dim3 tb(32, 8);
  #define GARGS Cf_, Cb_, MOE0b, MOE1b, TOK, PROB, SLOT, POFF, CNT

  // projection: Xb = bf16(vis @ proj_w + proj_b)
  tconv_kernel<<<dim3(1024 / 32, 1536 / 64), tb, 0, stream>>>(proj_w, Wproj, 1536, 1024);
  conv_kernel<<<(8192 * 1536 / 4) / 256, 256, 0, stream>>>(vis, VISb);
  {
    float* Cf_ = nullptr; u16* Cb_ = Xb;
    gemm_bt<1><<<dim3(8, 64), 256, 0, stream>>>(VISb, Wproj, proj_b, GARGS, 1024, 1536);
  }
  pe_kernel<<<8192 * 1024 / 4 / 256, 256, 0, stream>>>(Xb);

  for (int l = 0; l < 4; ++l) {
    tconv4_kernel<<<10240, tb, 0, stream>>>(
        in_proj_w + (size_t)l * 1024 * 3072, out_proj_w + (size_t)l * 1024 * 1024,
        ew1 + (size_t)l * 4 * 1024 * 2048, ew2 + (size_t)l * 4 * 2048 * 1024,
        Wqkv, Wout, We1, We2);

    {
      float* Cf_ = nullptr; u16* Cb_ = QKVb;
      gemm_bt<1><<<dim3(24, 64), 256, 0, stream>>>(Xb, Wqkv, in_proj_b + l * 3072, GARGS, 3072, 1024);
    }
    attn_mfma_kernel<<<512, 256, 0, stream>>>(QKVb, ATTb);
    {
      float* Cf_ = nullptr; u16* Cb_ = Xb;       // outproj + residual fused into Xb (RMW)
      gemm_bt<5><<<dim3(8, 64), 256, 0, stream>>>(ATTb, Wout, out_proj_b + l * 1024, GARGS, 1024, 1024);
    }
    // pure LN + router (in-place on Xb)
    ln_kernel<<<8192, 256, 0, stream>>>(Xb, ln1_g + l * 1024, ln1_b + l * 1024,
                                        router_w + (size_t)l * 4096, router_b + l * 4,
                                        CHOICE, PROB2);
    build_lists_kernel<<<1, 256, 0, stream>>>(CHOICE, PROB2, CNT, POFF, TOK, PROB, SLOT);
    {
      float* Cf_ = nullptr; u16* Cb_ = H;        // moe1: all experts, one launch
      gemm_bt<2><<<dim3(16, 136), 256, 0, stream>>>(Xb, We1, eb1 + (size_t)l * 4 * 2048, GARGS, 2048, 1024);
    }
    {
      float* Cf_ = nullptr; u16* Cb_ = nullptr;  // moe2: all experts, one launch
      gemm_bt<3><<<dim3(8, 136), 256, 0, stream>>>(H, We2, eb2 + (size_t)l * 4 * 1024, GARGS, 1024, 2048);
    }
    // fused residual + ln2 (+ pooling score on last layer), in-place on Xb
    ln2_kernel<<<8192, 256, 0, stream>>>(Xb, MOE0b, MOE1b, ln2_g + l * 1024, ln2_b + l * 1024,
                                         (l == 3) ? attn_w : nullptr, attn_b, S);
  }

  pool_kernel<<<64, 256, 0, stream>>>(Xb, S, POOL);
  heads_kernel<<<256, 256, 0, stream>>>(POOL, heads_w, heads_b, out);
  #undef GARGS
}

// Round 16
// 1794.772 us; speedup vs baseline: 1.0394x; 1.0394x over previous
//
#include <hip/hip_runtime.h>
#include <hip/hip_bf16.h>

typedef unsigned short u16;
typedef unsigned int u32;
using short8 = __attribute__((ext_vector_type(8))) short;
using f32x4  = __attribute__((ext_vector_type(4))) float;

// ---------- helpers ----------
__device__ __forceinline__ u16 f2bu(float f) {            // f32 -> bf16 bits (RNE)
  u32 u = __builtin_bit_cast(u32, f);
  u32 r = u + 0x7fffu + ((u >> 16) & 1u);
  return (u16)(r >> 16);
}
__device__ __forceinline__ float bu2f(u16 u) {             // bf16 bits -> f32
  u32 x = ((u32)u) << 16;
  return __builtin_bit_cast(float, x);
}
__device__ __forceinline__ float waveRedSum(float v) {
  #pragma unroll
  for (int off = 32; off > 0; off >>= 1) v += __shfl_xor(v, off, 64);
  return v;
}
__device__ __forceinline__ void gload16(const void* g, void* l) {
  __builtin_amdgcn_global_load_lds((const __attribute__((address_space(1))) u32*)g,
                                   (__attribute__((address_space(3))) u32*)l, 16, 0, 0);
}

// ---------- 128x128 GEMM, BK=64 + both-sides XOR swizzle (proven r13), T1 XCD swizzle ----------
// MODE 0: Cf f32 | MODE 1: Cb bf16 | MODE 2: moe1 gather-A(tok)+relu -> Cb | MODE 3: moe2 scatter*prob
template<int MODE>
__global__ __launch_bounds__(256) void gemm_bt(
    const u16* __restrict__ A, const u16* __restrict__ Bt, const float* __restrict__ bias,
    float* __restrict__ Cf, u16* __restrict__ Cb, u16* __restrict__ M0, u16* __restrict__ M1,
    const int* __restrict__ tok, const float* __restrict__ prob, const int* __restrict__ slot,
    const int* __restrict__ poff, const int* __restrict__ cnts,
    int N, int K)
{
  const int gx = gridDim.x;
  const int nwg = gx * gridDim.y;
  int lid = blockIdx.y * gx + blockIdx.x;
  lid = (lid & 7) * (nwg >> 3) + (lid >> 3);
  const int brow = (lid / gx) << 7, bcol = (lid % gx) << 7;

  int e = 0, rowEnd = 0;
  const u16* Bw = Bt;
  const float* bw = bias;
  if constexpr (MODE == 2 || MODE == 3) {
    if (brow >= poff[4]) return;
    #pragma unroll
    for (int q = 1; q < 4; ++q) if (brow >= poff[q]) e = q;
    rowEnd = poff[e] + cnts[e];
    Bw = Bt + (size_t)e * N * K;
    bw = bias + e * N;
  }

  __shared__ __align__(16) u16 As[128 * 64];
  __shared__ __align__(16) u16 Bs[128 * 64];
  const int tid = threadIdx.x;
  const int wave = tid >> 6, lane = tid & 63;
  const int wr = wave >> 1, wc = wave & 1;
  const int r = lane & 15, kg = lane >> 4;

  f32x4 acc[4][4];
  #pragma unroll
  for (int m = 0; m < 4; ++m)
    #pragma unroll
    for (int n = 0; n < 4; ++n) acc[m][n] = f32x4{0.f, 0.f, 0.f, 0.f};

  const u16* aSrc[4];
  const u16* bSrc[4];
  const u16* Bb = Bw + (size_t)bcol * K;
  #pragma unroll
  for (int q = 0; q < 4; ++q) {
    const int cid = (q << 8) + (wave << 6) + lane;
    const int row = cid >> 3, c = cid & 7;
    const int scol = (c ^ (row & 7)) << 3;
    size_t ar;
    if constexpr (MODE == 2) {
      const int g = brow + row;
      ar = (size_t)tok[(g < rowEnd) ? g : poff[e]];
    } else {
      ar = (size_t)(brow + row);
    }
    aSrc[q] = A + ar * K + scol;
    bSrc[q] = Bb + (size_t)row * K + scol;
  }
  const int swz0 = (kg ^ (r & 7)) << 3;
  const int swz1 = ((4 + kg) ^ (r & 7)) << 3;

  for (int k0 = 0; k0 < K; k0 += 64) {
    __syncthreads();
    #pragma unroll
    for (int q = 0; q < 4; ++q) {
      gload16(aSrc[q] + k0, &As[(((q << 8) + (wave << 6))) << 3]);
      gload16(bSrc[q] + k0, &Bs[(((q << 8) + (wave << 6))) << 3]);
    }
    __syncthreads();
    #pragma unroll
    for (int ks = 0; ks < 2; ++ks) {
      const int swz = ks ? swz1 : swz0;
      short8 a[4], b[4];
      #pragma unroll
      for (int m = 0; m < 4; ++m)
        a[m] = *(const short8*)&As[(((wr << 6) + (m << 4) + r) << 6) + swz];
      #pragma unroll
      for (int n = 0; n < 4; ++n)
        b[n] = *(const short8*)&Bs[(((wc << 6) + (n << 4) + r) << 6) + swz];
      #pragma unroll
      for (int m = 0; m < 4; ++m)
        #pragma unroll
        for (int n = 0; n < 4; ++n)
          acc[m][n] = __builtin_amdgcn_mfma_f32_16x16x32_bf16(a[m], b[n], acc[m][n], 0, 0, 0);
    }
  }

  if constexpr (MODE == 3) {
    #pragma unroll
    for (int m = 0; m < 4; ++m) {
      #pragma unroll
      for (int i4 = 0; i4 < 4; ++i4) {
        const int row = brow + (wr << 6) + (m << 4) + (kg << 2) + i4;
        if (row < rowEnd) {
          const int t = tok[row];
          const float pp = prob[row];
          u16* dst = slot[row] ? M1 : M0;
          #pragma unroll
          for (int n = 0; n < 4; ++n) {
            const int col = bcol + (wc << 6) + (n << 4) + r;
            dst[(size_t)t * N + col] = f2bu((acc[m][n][i4] + bw[col]) * pp);
          }
        }
      }
    }
  } else {
    #pragma unroll
    for (int m = 0; m < 4; ++m) {
      #pragma unroll
      for (int n = 0; n < 4; ++n) {
        const int col = bcol + (wc << 6) + (n << 4) + r;
        const float bv = bw[col];
        #pragma unroll
        for (int i4 = 0; i4 < 4; ++i4) {
          const int row = brow + (wr << 6) + (m << 4) + (kg << 2) + i4;
          const float v = acc[m][n][i4] + bv;
          const size_t off = (size_t)row * N + col;
          if constexpr (MODE == 0) Cf[off] = v;
          else if constexpr (MODE == 1) Cb[off] = f2bu(v);
          else Cb[off] = f2bu(fmaxf(v, 0.f));
        }
      }
    }
  }
}

// ---------- transpose+convert tile body v2: 64(k) x 32(n), vectorized short8 writes ----------
__device__ __forceinline__ void tconv_tile64(const float* __restrict__ s, u16* __restrict__ d,
                                             int K, int N, int n0, int k0)
{
  __shared__ float t[64][33];
  const int x = threadIdx.x, y = threadIdx.y;     // (32,8)
  #pragma unroll
  for (int j = 0; j < 8; ++j)
    t[y + 8 * j][x] = s[(size_t)(k0 + y + 8 * j) * N + n0 + x];
  __syncthreads();
  const int tid = y * 32 + x;
  const int nl = tid >> 3, kl = (tid & 7) << 3;
  short8 w;
  #pragma unroll
  for (int jj = 0; jj < 8; ++jj) w[jj] = (short)f2bu(t[kl + jj][nl]);
  *(short8*)(d + (size_t)(n0 + nl) * K + k0 + kl) = w;
}

// ---------- generic transpose+convert (proj only): grid (N/32, K/64) ----------
__global__ __launch_bounds__(256) void tconv_kernel(const float* __restrict__ src, u16* __restrict__ dst,
                                                    int K, int N)
{
  tconv_tile64(src, dst, K, N, blockIdx.x << 5, blockIdx.y << 6);
}

// ---------- per-layer fused weight conversion (10240 blocks) ----------
__global__ __launch_bounds__(256) void tconv4_kernel(
    const float* __restrict__ wqkv_s, const float* __restrict__ wout_s,
    const float* __restrict__ we1_s, const float* __restrict__ we2_s,
    u16* __restrict__ wqkv_d, u16* __restrict__ wout_d,
    u16* __restrict__ we1_d, u16* __restrict__ we2_d)
{
  const int bid = blockIdx.x;
  if (bid < 1536) {            // Wqkv: K=1024 (16 k-tiles), N=3072 (96 n-tiles)
    tconv_tile64(wqkv_s, wqkv_d, 1024, 3072, (bid % 96) << 5, (bid / 96) << 6);
  } else if (bid < 2048) {     // Wout: 16 x 32
    const int b2 = bid - 1536;
    tconv_tile64(wout_s, wout_d, 1024, 1024, (b2 % 32) << 5, (b2 / 32) << 6);
  } else if (bid < 6144) {     // We1[e]: K=1024 (16), N=2048 (64)
    const int b2 = bid - 2048;
    const int ee = b2 >> 10, rr = b2 & 1023;
    tconv_tile64(we1_s + (size_t)ee * 2048 * 1024, we1_d + (size_t)ee * 2048 * 1024,
                 1024, 2048, (rr % 64) << 5, (rr / 64) << 6);
  } else {                     // We2[e]: K=2048 (32), N=1024 (32)
    const int b2 = bid - 6144;
    const int ee = b2 >> 10, rr = b2 & 1023;
    tconv_tile64(we2_s + (size_t)ee * 1024 * 2048, we2_d + (size_t)ee * 1024 * 2048,
                 2048, 1024, (rr % 32) << 5, (rr / 32) << 6);
  }
}

// ---------- f32 -> bf16 elementwise ----------
__global__ __launch_bounds__(256) void conv_kernel(const float* __restrict__ in, u16* __restrict__ out)
{
  const size_t i = ((size_t)blockIdx.x * 256 + threadIdx.x) * 4;
  float4 v = *(const float4*)(in + i);
  *(ushort4*)(out + i) = make_ushort4(f2bu(v.x), f2bu(v.y), f2bu(v.z), f2bu(v.w));
}

// ---------- add sinusoidal positional encoding, bf16 in-place ----------
__global__ __launch_bounds__(256) void pe_kernel(u16* __restrict__ Xb)
{
  const int idx = (blockIdx.x * 256 + threadIdx.x) * 4;
  const int s = (idx >> 10) & 127;
  ushort4 v = *(const ushort4*)(Xb + idx);
  float o[4];
  const u16 vv[4] = {v.x, v.y, v.z, v.w};
  #pragma unroll
  for (int j = 0; j < 4; ++j) {
    const int d = (idx + j) & 1023;
    const float de = (float)(d & ~1);
    const float ang = (float)s * expf(de * (-9.210340371976184f / 1024.f));
    const float pe = (d & 1) ? cosf(ang) : sinf(ang);
    o[j] = bu2f(vv[j]) + pe;
  }
  *(ushort4*)(Xb + idx) = make_ushort4(f2bu(o[0]), f2bu(o[1]), f2bu(o[2]), f2bu(o[3]));
}

// ---------- fused residual(bf16 O16) + LN + router: bf16 in-place, vectorized ----------
__global__ __launch_bounds__(256) void ln_kernel(u16* __restrict__ Xb, const u16* __restrict__ R,
    const float* __restrict__ g, const float* __restrict__ be,
    const float* __restrict__ rw, const float* __restrict__ rb,
    int* __restrict__ choice, float* __restrict__ prob2)
{
  const int token = blockIdx.x;
  const size_t base = (size_t)token << 10;
  const int tid = threadIdx.x;
  const int d0 = tid << 2;
  ushort4 xv = *(const ushort4*)(Xb + base + d0);
  ushort4 rv = *(const ushort4*)(R + base + d0);
  float vals[4] = {bu2f(xv.x) + bu2f(rv.x), bu2f(xv.y) + bu2f(rv.y),
                   bu2f(xv.z) + bu2f(rv.z), bu2f(xv.w) + bu2f(rv.w)};
  float s = 0.f, s2 = 0.f;
  #pragma unroll
  for (int j = 0; j < 4; ++j) { s += vals[j]; s2 += vals[j] * vals[j]; }
  s = waveRedSum(s); s2 = waveRedSum(s2);
  __shared__ float rs[4], rs2[4];
  __shared__ float rl[4][4];
  const int wave = tid >> 6, lane = tid & 63;
  if (lane == 0) { rs[wave] = s; rs2[wave] = s2; }
  __syncthreads();
  s = rs[0] + rs[1] + rs[2] + rs[3];
  s2 = rs2[0] + rs2[1] + rs2[2] + rs2[3];
  const float mean = s * (1.f / 1024.f);
  const float var = s2 * (1.f / 1024.f) - mean * mean;
  const float inv = rsqrtf(var + 1e-5f);
  const float4 gv = *(const float4*)(g + d0);
  const float4 bv = *(const float4*)(be + d0);
  float y[4];
  y[0] = (vals[0] - mean) * inv * gv.x + bv.x;
  y[1] = (vals[1] - mean) * inv * gv.y + bv.y;
  y[2] = (vals[2] - mean) * inv * gv.z + bv.z;
  y[3] = (vals[3] - mean) * inv * gv.w + bv.w;
  *(ushort4*)(Xb + base + d0) = make_ushort4(f2bu(y[0]), f2bu(y[1]), f2bu(y[2]), f2bu(y[3]));
  float l0 = 0.f, l1 = 0.f, l2 = 0.f, l3 = 0.f;
  #pragma unroll
  for (int j = 0; j < 4; ++j) {
    const float4 w = *(const float4*)(rw + ((size_t)(d0 + j) << 2));
    l0 += y[j] * w.x; l1 += y[j] * w.y; l2 += y[j] * w.z; l3 += y[j] * w.w;
  }
  l0 = waveRedSum(l0); l1 = waveRedSum(l1); l2 = waveRedSum(l2); l3 = waveRedSum(l3);
  if (lane == 0) { rl[wave][0] = l0; rl[wave][1] = l1; rl[wave][2] = l2; rl[wave][3] = l3; }
  __syncthreads();
  if (tid == 0) {
    float v[4];
    #pragma unroll
    for (int q = 0; q < 4; ++q)
      v[q] = rl[0][q] + rl[1][q] + rl[2][q] + rl[3][q] + rb[q];
    int i1 = 0;
    for (int q = 1; q < 4; ++q) if (v[q] > v[i1]) i1 = q;   // earliest-max tie rule
    int i2 = (i1 == 0) ? 1 : 0;
    for (int q = 0; q < 4; ++q) if (q != i1 && v[q] > v[i2]) i2 = q;
    const float p2 = __expf(v[i2] - v[i1]);
    const float is = 1.f / (1.f + p2);
    choice[token] = i1 | (i2 << 8);
    prob2[token * 2]     = is;
    prob2[token * 2 + 1] = p2 * is;
  }
}

// ---------- fused residual + LN (2 MOE slots) + optional pooling score: bf16 in-place ----------
__global__ __launch_bounds__(256) void ln2_kernel(u16* __restrict__ Xb,
    const u16* __restrict__ R0, const u16* __restrict__ R1,
    const float* __restrict__ g, const float* __restrict__ be,
    const float* __restrict__ aw, const float* __restrict__ ab, float* __restrict__ S)
{
  const int token = blockIdx.x;
  const size_t base = (size_t)token << 10;
  const int tid = threadIdx.x;
  const int d0 = tid << 2;
  ushort4 xv = *(const ushort4*)(Xb + base + d0);
  ushort4 r0 = *(const ushort4*)(R0 + base + d0);
  ushort4 r1 = *(const ushort4*)(R1 + base + d0);
  float vals[4] = {bu2f(xv.x) + (bu2f(r0.x) + bu2f(r1.x)),
                   bu2f(xv.y) + (bu2f(r0.y) + bu2f(r1.y)),
                   bu2f(xv.z) + (bu2f(r0.z) + bu2f(r1.z)),
                   bu2f(xv.w) + (bu2f(r0.w) + bu2f(r1.w))};
  float s = 0.f, s2 = 0.f;
  #pragma unroll
  for (int j = 0; j < 4; ++j) { s += vals[j]; s2 += vals[j] * vals[j]; }
  s = waveRedSum(s); s2 = waveRedSum(s2);
  __shared__ float rs[4], rs2[4];
  __shared__ float rsc[4];
  const int wave = tid >> 6, lane = tid & 63;
  if (lane == 0) { rs[wave] = s; rs2[wave] = s2; }
  __syncthreads();
  s = rs[0] + rs[1] + rs[2] + rs[3];
  s2 = rs2[0] + rs2[1] + rs2[2] + rs2[3];
  const float mean = s * (1.f / 1024.f);
  const float var = s2 * (1.f / 1024.f) - mean * mean;
  const float inv = rsqrtf(var + 1e-5f);
  const float4 gv = *(const float4*)(g + d0);
  const float4 bv = *(const float4*)(be + d0);
  float y[4];
  y[0] = (vals[0] - mean) * inv * gv.x + bv.x;
  y[1] = (vals[1] - mean) * inv * gv.y + bv.y;
  y[2] = (vals[2] - mean) * inv * gv.z + bv.z;
  y[3] = (vals[3] - mean) * inv * gv.w + bv.w;
  *(ushort4*)(Xb + base + d0) = make_ushort4(f2bu(y[0]), f2bu(y[1]), f2bu(y[2]), f2bu(y[3]));
  if (aw) {
    const float4 av = *(const float4*)(aw + d0);
    float sc = y[0] * av.x + y[1] * av.y + y[2] * av.z + y[3] * av.w;
    sc = waveRedSum(sc);
    if (lane == 0) rsc[wave] = sc;
    __syncthreads();
    if (tid == 0) S[token] = rsc[0] + rsc[1] + rsc[2] + rsc[3] + ab[0];
  }
}

// ---------- MFMA attention per (b,h): Pb aliased onto Kb -> 69.6 KB LDS, 2 blocks/CU ----------
#define LDW 136
__global__ __launch_bounds__(256) void attn_mfma_kernel(const u16* __restrict__ QKVb, u16* __restrict__ ATTb)
{
  __shared__ __align__(16) u16 Kb[128 * LDW];
  __shared__ __align__(16) u16 Vt[128 * LDW];
  u16* Pb = Kb;
  const int b = blockIdx.x >> 3, h = blockIdx.x & 7;
  const int tid = threadIdx.x;
  const int wave = tid >> 6, lane = tid & 63;
  const int r = lane & 15, kg = lane >> 4;
  const u16* base = QKVb + (size_t)b * 128 * 3072 + h * 128;

  for (int i = tid; i < 128 * 16; i += 256) {
    const int row = i >> 4, c8 = (i & 15) << 3;
    *(short8*)&Kb[row * LDW + c8] = *(const short8*)(base + (size_t)row * 3072 + 1024 + c8);
  }
  for (int i = tid; i < 128 * 128; i += 256) {
    const int d = i & 127, key = i >> 7;
    Vt[d * LDW + key] = base[(size_t)key * 3072 + 2048 + d];
  }

  short8 a[2][4];
  #pragma unroll
  for (int m = 0; m < 2; ++m) {
    const int row = wave * 32 + m * 16 + r;
    const u16* qp = base + (size_t)row * 3072;
    #pragma unroll
    for (int ks = 0; ks < 4; ++ks)
      a[m][ks] = *(const short8*)(qp + ks * 32 + kg * 8);
  }
  __syncthreads();

  f32x4 acc[2][8];
  #pragma unroll
  for (int m = 0; m < 2; ++m)
    #pragma unroll
    for (int n = 0; n < 8; ++n) acc[m][n] = f32x4{0.f, 0.f, 0.f, 0.f};
  #pragma unroll
  for (int n = 0; n < 8; ++n) {
    #pragma unroll
    for (int ks = 0; ks < 4; ++ks) {
      short8 bf = *(const short8*)&Kb[(n * 16 + r) * LDW + ks * 32 + kg * 8];
      #pragma unroll
      for (int m = 0; m < 2; ++m)
        acc[m][n] = __builtin_amdgcn_mfma_f32_16x16x32_bf16(a[m][ks], bf, acc[m][n], 0, 0, 0);
    }
  }
  __syncthreads();   // all waves done reading Kb before Pb (same memory) is written

  const float sc = 0.08838834764831845f;
  #pragma unroll
  for (int m = 0; m < 2; ++m) {
    #pragma unroll
    for (int i = 0; i < 4; ++i) {
      float mx = -1e30f;
      #pragma unroll
      for (int n = 0; n < 8; ++n) mx = fmaxf(mx, acc[m][n][i]);
      #pragma unroll
      for (int msk = 1; msk < 16; msk <<= 1) mx = fmaxf(mx, __shfl_xor(mx, msk, 64));
      float s = 0.f;
      #pragma unroll
      for (int n = 0; n < 8; ++n) { float pv = __expf((acc[m][n][i] - mx) * sc); acc[m][n][i] = pv; s += pv; }
      #pragma unroll
      for (int msk = 1; msk < 16; msk <<= 1) s += __shfl_xor(s, msk, 64);
      const float inv = 1.f / s;
      #pragma unroll
      for (int n = 0; n < 8; ++n) {
        const int prow = wave * 32 + m * 16 + kg * 4 + i;
        Pb[prow * LDW + n * 16 + r] = f2bu(acc[m][n][i] * inv);
      }
    }
  }

  f32x4 oacc[2][8];
  #pragma unroll
  for (int m = 0; m < 2; ++m)
    #pragma unroll
    for (int n = 0; n < 8; ++n) oacc[m][n] = f32x4{0.f, 0.f, 0.f, 0.f};
  #pragma unroll
  for (int ks = 0; ks < 4; ++ks) {
    short8 pa[2];
    #pragma unroll
    for (int m = 0; m < 2; ++m)
      pa[m] = *(const short8*)&Pb[(wave * 32 + m * 16 + r) * LDW + ks * 32 + kg * 8];
    #pragma unroll
    for (int n = 0; n < 8; ++n) {
      short8 vb = *(const short8*)&Vt[(n * 16 + r) * LDW + ks * 32 + kg * 8];
      #pragma unroll
      for (int m = 0; m < 2; ++m)
        oacc[m][n] = __builtin_amdgcn_mfma_f32_16x16x32_bf16(pa[m], vb, oacc[m][n], 0, 0, 0);
    }
  }

  u16* op = ATTb + ((size_t)b * 128) * 1024 + h * 128;
  #pragma unroll
  for (int m = 0; m < 2; ++m) {
    #pragma unroll
    for (int n = 0; n < 8; ++n) {
      #pragma unroll
      for (int i = 0; i < 4; ++i) {
        const int row = wave * 32 + m * 16 + kg * 4 + i;
        op[(size_t)row * 1024 + n * 16 + r] = f2bu(oacc[m][n][i]);
      }
    }
  }
}
#undef LDW

// ---------- build lists: 4 waves, wave e scans for expert e (atomic-free, deterministic) ----------
__global__ __launch_bounds__(256) void build_lists_kernel(
    const int* __restrict__ choice, const float* __restrict__ prob2,
    int* __restrict__ cnt, int* __restrict__ poff,
    int* __restrict__ tok, float* __restrict__ prob, int* __restrict__ slot)
{
  const int tid = threadIdx.x;
  const int e = tid >> 6, lane = tid & 63;
  const int t0 = lane << 7;
  int mycount = 0;
  for (int j = 0; j < 128; ++j) {
    const int c = choice[t0 + j];
    mycount += (((c & 255) == e) || ((c >> 8) == e)) ? 1 : 0;
  }
  int incl = mycount;
  #pragma unroll
  for (int off = 1; off < 64; off <<= 1) {
    const int t = __shfl_up(incl, off, 64);
    if (lane >= off) incl += t;
  }
  __shared__ int totals[4];
  if (lane == 63) totals[e] = incl;
  __syncthreads();
  int base = 0;
  #pragma unroll
  for (int q = 0; q < 4; ++q)
    if (q < e) base += (totals[q] + 255) & ~255;
  int pos = base + incl - mycount;
  for (int j = 0; j < 128; ++j) {
    const int token = t0 + j;
    const int c = choice[token];
    const int m = ((c & 255) == e) ? 1 : (((c >> 8) == e) ? 2 : 0);
    if (m) {
      tok[pos] = token;
      prob[pos] = prob2[token * 2 + (m - 1)];
      slot[pos] = m - 1;
      ++pos;
    }
  }
  if (lane == 0) {
    cnt[e] = totals[e];
    poff[e] = base;
    if (e == 3) poff[4] = base + ((totals[3] + 255) & ~255);
  }
}

// ---------- softmax over S per batch + weighted pool (bf16 X) ----------
__global__ __launch_bounds__(256) void pool_kernel(const u16* __restrict__ Xb, const float* __restrict__ S,
                                                   float* __restrict__ P)
{
  const int b = blockIdx.x;
  const int tid = threadIdx.x;
  __shared__ float p[128];
  if (tid < 128) p[tid] = S[b * 128 + tid];
  __syncthreads();
  float mx = -1e30f;
  for (int t = 0; t < 128; ++t) mx = fmaxf(mx, p[t]);
  float sum = 0.f;
  for (int t = 0; t < 128; ++t) sum += __expf(p[t] - mx);
  const float inv = 1.f / sum;
  __syncthreads();
  if (tid < 128) p[tid] = __expf(p[tid] - mx) * inv;
  __syncthreads();
  float acc[4] = {0.f, 0.f, 0.f, 0.f};
  for (int t = 0; t < 128; ++t) {
    const float pt = p[t];
    const u16* xp = Xb + ((size_t)(b * 128 + t) << 10) + tid;
    #pragma unroll
    for (int j = 0; j < 4; ++j) acc[j] += pt * bu2f(xp[j << 8]);
  }
  #pragma unroll
  for (int j = 0; j < 4; ++j) P[((size_t)b << 10) + tid + (j << 8)] = acc[j];
}

// ---------- task heads ----------
__global__ __launch_bounds__(256) void heads_kernel(const float* __restrict__ P, const float* __restrict__ hw,
    const float* __restrict__ hb, float* __restrict__ out)
{
  const int idx = blockIdx.x * 4 + (threadIdx.x >> 6);
  const int lane = threadIdx.x & 63;
  const int t = idx >> 8, b = (idx >> 2) & 63, c = idx & 3;
  const float* pp = P + ((size_t)b << 10);
  const float* wp = hw + (size_t)t * 4096 + c;
  float s = 0.f;
  #pragma unroll
  for (int j = 0; j < 16; ++j) { const int k = lane + (j << 6); s += pp[k] * wp[(size_t)k << 2]; }
  s = waveRedSum(s);
  if (lane == 0) out[idx] = s + hb[t * 4 + c];
}

// ---------- host ----------
extern "C" void kernel_launch(void* const* d_in, const int* in_sizes, int n_in,
                              void* d_out, int out_size, void* d_ws, size_t ws_size,
                              hipStream_t stream)
{
  (void)in_sizes; (void)n_in; (void)out_size; (void)ws_size;
  const float* vis        = (const float*)d_in[0];
  const float* proj_w     = (const float*)d_in[1];
  const float* proj_b     = (const float*)d_in[2];
  const float* in_proj_w  = (const float*)d_in[3];
  const float* in_proj_b  = (const float*)d_in[4];
  const float* out_proj_w = (const float*)d_in[5];
  const float* out_proj_b = (const float*)d_in[6];
  const float* ln1_g      = (const float*)d_in[7];
  const float* ln1_b      = (const float*)d_in[8];
  const float* ln2_g      = (const float*)d_in[9];
  const float* ln2_b      = (const float*)d_in[10];
  const float* router_w   = (const float*)d_in[11];
  const float* router_b   = (const float*)d_in[12];
  const float* ew1        = (const float*)d_in[13];
  const float* eb1        = (const float*)d_in[14];
  const float* ew2        = (const float*)d_in[15];
  const float* eb2        = (const float*)d_in[16];
  const float* attn_w     = (const float*)d_in[17];
  const float* attn_b     = (const float*)d_in[18];
  const float* heads_w    = (const float*)d_in[19];
  const float* heads_b    = (const float*)d_in[20];
  float* out = (float*)d_out;

  char* p = (char*)d_ws;
  auto take = [&](size_t bytes) -> char* {
    char* q = p; p += (bytes + 255) & ~(size_t)255; return q;
  };
  u16*   Xb   = (u16*)  take(8192ULL * 1024 * 2);
  char*  QKVr = take(104857600ULL);              // QKVb(50.3M) | O16(16.8M) | [H 71.3M][MOE0b][MOE1b]
  u16*   ATTb = (u16*)  take(8192ULL * 1024 * 2);
  int*   CNT  = (int*)  take(4 * 4);
  int*   POFF = (int*)  take(5 * 4);
  int*   CHOICE = (int*)take(8192ULL * 4);
  float* PROB2  = (float*)take(8192ULL * 2 * 4);
  int*   TOK  = (int*)  take(17408ULL * 4);
  float* PROB = (float*)take(17408ULL * 4);
  int*   SLOT = (int*)  take(17408ULL * 4);
  float* S    = (float*)take(8192ULL * 4);
  float* POOL = (float*)take(64ULL * 1024 * 4);
  u16*   Wqkv = (u16*)  take(3072ULL * 1024 * 2);
  u16*   Wout = (u16*)  take(1024ULL * 1024 * 2);
  u16*   We1  = (u16*)  take(4ULL * 2048 * 1024 * 2);
  u16*   We2  = (u16*)  take(4ULL * 1024 * 2048 * 2);
  // aliases into QKVr (time-disjoint): QKVb [qkv->attn]; O16 [outproj->ln1]; H [moe1->moe2]; MOEb [moe2->ln2]
  u16*   QKVb  = (u16*)QKVr;
  u16*   O16   = (u16*)QKVr;
  u16*   H     = (u16*)QKVr;                      // 17408 x 2048 bf16 = 71.3MB
  u16*   MOE0b = (u16*)(QKVr + 71303168);
  u16*   MOE1b = (u16*)(QKVr + 71303168 + 16777216);
  u16*   Wproj = We1;                              // pre-layer-0 only
  u16*   VISb  = (u16*)QKVr;                       // pre-layer-0 only (25.2MB)

  const dim3 tb(32, 8);
  #define GARGS Cf_, Cb_, MOE0b, MOE1b, TOK, PROB, SLOT, POFF, CNT

  // projection: Xb = bf16(vis @ proj_w + proj_b)
  tconv_kernel<<<dim3(1024 / 32, 1536 / 64), tb, 0, stream>>>(proj_w, Wproj, 1536, 1024);
  conv_kernel<<<(8192 * 1536 / 4) / 256, 256, 0, stream>>>(vis, VISb);
  {
    float* Cf_ = nullptr; u16* Cb_ = Xb;
    gemm_bt<1><<<dim3(8, 64), 256, 0, stream>>>(VISb, Wproj, proj_b, GARGS, 1024, 1536);
  }
  pe_kernel<<<8192 * 1024 / 4 / 256, 256, 0, stream>>>(Xb);

  for (int l = 0; l < 4; ++l) {
    tconv4_kernel<<<10240, tb, 0, stream>>>(
        in_proj_w + (size_t)l * 1024 * 3072, out_proj_w + (size_t)l * 1024 * 1024,
        ew1 + (size_t)l * 4 * 1024 * 2048, ew2 + (size_t)l * 4 * 2048 * 1024,
        Wqkv, Wout, We1, We2);

    {
      float* Cf_ = nullptr; u16* Cb_ = QKVb;
      gemm_bt<1><<<dim3(24, 64), 256, 0, stream>>>(Xb, Wqkv, in_proj_b + l * 3072, GARGS, 3072, 1024);
    }
    attn_mfma_kernel<<<512, 256, 0, stream>>>(QKVb, ATTb);
    {
      float* Cf_ = nullptr; u16* Cb_ = O16;      // bf16 outproj result (no RMW)
      gemm_bt<1><<<dim3(8, 64), 256, 0, stream>>>(ATTb, Wout, out_proj_b + l * 1024, GARGS, 1024, 1024);
    }
    // fused residual + ln1 + router (in-place on Xb)
    ln_kernel<<<8192, 256, 0, stream>>>(Xb, O16, ln1_g + l * 1024, ln1_b + l * 1024,
                                        router_w + (size_t)l * 4096, router_b + l * 4,
                                        CHOICE, PROB2);
    build_lists_kernel<<<1, 256, 0, stream>>>(CHOICE, PROB2, CNT, POFF, TOK, PROB, SLOT);
    {
      float* Cf_ = nullptr; u16* Cb_ = H;        // moe1: all experts, one launch
      gemm_bt<2><<<dim3(16, 136), 256, 0, stream>>>(Xb, We1, eb1 + (size_t)l * 4 * 2048, GARGS, 2048, 1024);
    }
    {
      float* Cf_ = nullptr; u16* Cb_ = nullptr;  // moe2: all experts, one launch
      gemm_bt<3><<<dim3(8, 136), 256, 0, stream>>>(H, We2, eb2 + (size_t)l * 4 * 1024, GARGS, 1024, 2048);
    }
    // fused residual + ln2 (+ pooling score on last layer), in-place on Xb
    ln2_kernel<<<8192, 256, 0, stream>>>(Xb, MOE0b, MOE1b, ln2_g + l * 1024, ln2_b + l * 1024,
                                         (l == 3) ? attn_w : nullptr, attn_b, S);
  }

  pool_kernel<<<64, 256, 0, stream>>>(Xb, S, POOL);
  heads_kernel<<<256, 256, 0, stream>>>(POOL, heads_w, heads_b, out);
  #undef GARGS
}